// Round 1
// baseline (180.238 us; speedup 1.0000x reference)
//
#include <hip/hip_runtime.h>

// LengthRegulator: B=32, T=512, D=512, max_len=2048 (fixed by the problem).
// out[b, t, :] = x[b, searchsorted_right(cumsum(duration[b]), t), :] for
// t < sum(duration[b]), else zeros. mel_lengths[b] = max(sum, 1), stored as
// float at the tail of d_out (harness reads whole buffer as float32).

#define BB      32
#define TT      512
#define DD      512
#define MAXLEN  2048

// One block per batch: inclusive scan of duration[b, :] into csum, plus
// mel_lengths (as float) into the tail of d_out.
__global__ __launch_bounds__(TT) void lr_scan_kernel(
    const int* __restrict__ dur, int* __restrict__ csum,
    float* __restrict__ mel_out) {
  __shared__ int s[TT];
  const int b = blockIdx.x;
  const int t = threadIdx.x;
  s[t] = dur[b * TT + t];
  __syncthreads();
  // Hillis-Steele inclusive scan over 512 elements (9 steps).
#pragma unroll
  for (int off = 1; off < TT; off <<= 1) {
    int v = (t >= off) ? s[t - off] : 0;
    __syncthreads();
    s[t] += v;
    __syncthreads();
  }
  csum[b * TT + t] = s[t];
  if (t == TT - 1) {
    int ds = s[TT - 1];
    mel_out[b] = (float)(ds > 1 ? ds : 1);
  }
}

// One 128-thread block per output frame. Each thread moves one float4
// (512 floats = 128 float4 per row). Binary search is wave-uniform
// (same addresses across lanes -> L1 broadcast).
__global__ __launch_bounds__(128) void lr_gather_kernel(
    const float4* __restrict__ x, const int* __restrict__ csum,
    float4* __restrict__ out) {
  const int frame = blockIdx.x;      // 0 .. B*MAXLEN-1
  const int b = frame >> 11;         // / MAXLEN
  const int t = frame & (MAXLEN - 1);
  const int* __restrict__ c = csum + b * TT;
  const int dsum = c[TT - 1];

  float4 val = make_float4(0.f, 0.f, 0.f, 0.f);
  if (t < dsum) {
    // searchsorted right: first j with c[j] > t
    int lo = 0, hi = TT;
    while (lo < hi) {
      int mid = (lo + hi) >> 1;
      if (c[mid] <= t) lo = mid + 1; else hi = mid;
    }
    int idx = lo < (TT - 1) ? lo : (TT - 1);
    val = x[((size_t)b * TT + idx) * (DD / 4) + threadIdx.x];
  }
  out[((size_t)b * MAXLEN + t) * (DD / 4) + threadIdx.x] = val;
}

extern "C" void kernel_launch(void* const* d_in, const int* in_sizes, int n_in,
                              void* d_out, int out_size, void* d_ws, size_t ws_size,
                              hipStream_t stream) {
  const float* x   = (const float*)d_in[0];
  const int*   dur = (const int*)d_in[1];
  // d_in[2] is max_len (=2048), static; hard-coded.
  float* out = (float*)d_out;
  int*   csum = (int*)d_ws;  // B*T ints = 64 KiB scratch

  float* mel_out = out + (size_t)BB * MAXLEN * DD;  // tail: 32 floats

  lr_scan_kernel<<<BB, TT, 0, stream>>>(dur, csum, mel_out);
  lr_gather_kernel<<<BB * MAXLEN, 128, 0, stream>>>(
      (const float4*)x, csum, (float4*)out);
}

// Round 3
// 173.089 us; speedup vs baseline: 1.0413x; 1.0413x over previous
//
#include <hip/hip_runtime.h>

// LengthRegulator: B=32, T=512, D=512, max_len=2048 (fixed by the problem).
// out[b, t, :] = x[b, searchsorted_right(cumsum(duration[b]), t), :] for
// t < sum(duration[b]), else zeros. mel_lengths[b] = max(sum, 1), stored as
// float at the tail of d_out (harness reads whole buffer as float32).
//
// Fused single-kernel design: each block owns (batch b, 64-frame chunk).
// It redundantly loads+scans duration[b,:] in LDS (cheap: 2 KiB, L2-hot),
// binary-searches its 64 frames in LDS (no global dependent-load chain),
// then streams 64 frames = 128 KiB of contiguous output with nontemporal
// float4 stores (output is never re-read; keep L2 for x reuse).

#define BB      32
#define TT      512
#define DD      512
#define MAXLEN  2048
#define CHUNK   64                 // frames per block
#define NCHUNK  (MAXLEN / CHUNK)   // 32 chunks per batch

// Native vector type: __builtin_nontemporal_store rejects HIP's float4 class.
typedef float f4 __attribute__((ext_vector_type(4)));

__global__ __launch_bounds__(512) void lr_fused_kernel(
    const int* __restrict__ dur, const f4* __restrict__ x,
    f4* __restrict__ out, float* __restrict__ mel_out) {
  __shared__ int s[TT];        // inclusive cumsum of duration[b,:]
  __shared__ int s_idx[CHUNK]; // phoneme index per frame (-1 = padding)

  const int b     = blockIdx.x >> 5;   // / NCHUNK
  const int chunk = blockIdx.x & (NCHUNK - 1);
  const int tid   = threadIdx.x;

  s[tid] = dur[b * TT + tid];
  __syncthreads();
  // Hillis-Steele inclusive scan over 512 elements (9 steps).
#pragma unroll
  for (int off = 1; off < TT; off <<= 1) {
    int v = (tid >= off) ? s[tid - off] : 0;
    __syncthreads();
    s[tid] += v;
    __syncthreads();
  }
  const int dsum = s[TT - 1];
  if (chunk == 0 && tid == 0) {
    mel_out[b] = (float)(dsum > 1 ? dsum : 1);
  }

  const int base = chunk * CHUNK;
  if (tid < CHUNK) {
    int t = base + tid;
    int v = -1;
    if (t < dsum) {
      // searchsorted right: first j with s[j] > t (LDS, ~9 iterations)
      int lo = 0, hi = TT;
      while (lo < hi) {
        int mid = (lo + hi) >> 1;
        if (s[mid] <= t) lo = mid + 1; else hi = mid;
      }
      v = lo < (TT - 1) ? lo : (TT - 1);
    }
    s_idx[tid] = v;
  }
  __syncthreads();

  // Copy: 512 threads move 4 frames x 128 float4 per iteration, 16 iters.
  const int lane = tid & 127;    // float4 lane within a frame row
  const int fsub = tid >> 7;     // 0..3: frame sub-slot per iteration
  const f4 zero = {0.f, 0.f, 0.f, 0.f};
#pragma unroll
  for (int it = 0; it < 16; ++it) {
    const int f = it * 4 + fsub;           // frame within chunk
    const int idx = s_idx[f];
    f4 v = zero;
    if (idx >= 0) {
      v = x[((size_t)b * TT + idx) * (DD / 4) + lane];
    }
    __builtin_nontemporal_store(
        v, &out[((size_t)b * MAXLEN + base + f) * (DD / 4) + lane]);
  }
}

extern "C" void kernel_launch(void* const* d_in, const int* in_sizes, int n_in,
                              void* d_out, int out_size, void* d_ws, size_t ws_size,
                              hipStream_t stream) {
  const float* x   = (const float*)d_in[0];
  const int*   dur = (const int*)d_in[1];
  // d_in[2] is max_len (=2048), static; hard-coded.
  float* out = (float*)d_out;
  float* mel_out = out + (size_t)BB * MAXLEN * DD;  // tail: 32 floats

  lr_fused_kernel<<<BB * NCHUNK, 512, 0, stream>>>(
      dur, (const f4*)x, (f4*)out, mel_out);
}